// Round 1
// baseline (1736.846 us; speedup 1.0000x reference)
//
#include <hip/hip_runtime.h>
#include <math.h>

// dims (hardcoded per reference)
#define B_TOT 2048
#define T_STEPS 50
#define F_DIM 64
#define R_RIMS 6
#define H_DIM 64
#define K_ACT 4
#define BB 8   // batch rows per block

__device__ __forceinline__ void fma4(float4& a, const float4 v, const float s) {
  a.x = fmaf(v.x, s, a.x); a.y = fmaf(v.y, s, a.y);
  a.z = fmaf(v.z, s, a.z); a.w = fmaf(v.w, s, a.w);
}
__device__ __forceinline__ float sigmoidf_(float x) { return 1.0f / (1.0f + __expf(-x)); }
__device__ __forceinline__ float tanhf_(float x) {
  float ax = fabsf(x);
  float e = __expf(-2.0f * ax);
  float t = (1.0f - e) / (1.0f + e);
  return copysignf(t, x);
}

// W_comb[r] = Wv @ W_ih[r] : [6][64][192]
__global__ void wcomb_kernel(const float* __restrict__ Wv, const float* __restrict__ Wih,
                             float* __restrict__ Wc) {
  int g = threadIdx.x;          // 0..191
  int f = blockIdx.x & 63;      // 0..63
  int r = blockIdx.x >> 6;      // 0..5
  float acc = 0.f;
#pragma unroll 8
  for (int v = 0; v < 128; ++v)
    acc = fmaf(Wv[f * 128 + v], Wih[(r * 128 + v) * 192 + g], acc);
  Wc[(r * 64 + f) * 192 + g] = acc;
}

__global__ __launch_bounds__(512, 1) void rims_kernel(
    const float* __restrict__ x, const float* __restrict__ statics,
    const float* __restrict__ maskp, const float* __restrict__ delta,
    const float* __restrict__ xlast, const float* __restrict__ xmean,
    const float* __restrict__ wdgp, const float* __restrict__ bdgp,
    const float* __restrict__ Wk, const float* __restrict__ Wq,
    const float* __restrict__ Whh, const float* __restrict__ bih,
    const float* __restrict__ bhh, const float* __restrict__ Wqc,
    const float* __restrict__ Wkc, const float* __restrict__ Wvc,
    const float* __restrict__ W1, const float* __restrict__ b1,
    const float* __restrict__ W2, const float* __restrict__ b2,
    const float* __restrict__ Wcomb, float* __restrict__ out) {
  // Activation tiles: [col][8] unpadded -> aligned float4 broadcast reads in GEMM phases.
  __shared__ float xh_T[64][8];
  __shared__ float h_T[6][64][8];
  __shared__ float hn_T[6][64][8];
  // Output tiles: pad 9 -> conflict-free lane-strided scalar access (gcd(9,32)=1).
  __shared__ float K0_T[64][9];
  __shared__ float Q_T[6][64][9];
  __shared__ float qc_T[6][128][9];
  __shared__ float kc_T[6][128][9];
  __shared__ float vc_T[6][64][9];
  __shared__ float bih_l[6 * 192];
  __shared__ float bhh_l[6 * 192];
  __shared__ float p0_l[8][6];
  __shared__ float act_l[8][6];

  const int tid = threadIdx.x;
  const int wave = tid >> 6;   // 0..7 ; doubles as batch-row index bb in per-row phases
  const int lane = tid & 63;
  const int b0 = blockIdx.x * BB;

  for (int i = tid; i < 6 * 192; i += 512) { bih_l[i] = bih[i]; bhh_l[i] = bhh[i]; }
  for (int i = tid; i < 6 * 64 * 8; i += 512) (&h_T[0][0][0])[i] = 0.f;

  const float wdg = wdgp[lane];
  const float bdg = bdgp[lane];
  const float xmv = xmean[(size_t)(b0 + wave) * 64 + lane];
  __syncthreads();

  for (int t = 0; t < T_STEPS; ++t) {
    // ---------------- X: GRU-D decay / imputation (thread = (row=wave, feat=lane))
    {
      size_t off = ((size_t)(b0 + wave) * T_STEPS + t) * 64 + lane;
      float xt = x[off], mt = maskp[off], dt = delta[off], xl = xlast[off];
      float gm = __expf(-fmaxf(fmaf(dt, wdg, bdg), 0.f));
      xh_T[lane][wave] = mt * xt + (1.f - mt) * (gm * xl + (1.f - gm) * xmv);
    }
    __syncthreads();
    // ---------------- G0: K0 = xh@Wk (wave 0), Q[r] = h[r]@Wq[r] (waves 1..6)
    if (wave < 7) {
      const float* Ws = (wave == 0) ? Wk : (Wq + (wave - 1) * 64 * 64);
      const float(*src)[8] = (wave == 0) ? xh_T : h_T[wave - 1];
      float4 aL = {0, 0, 0, 0}, aH = {0, 0, 0, 0};
#pragma unroll 8
      for (int l2 = 0; l2 < 64; ++l2) {
        float w = Ws[l2 * 64 + lane];
        float4 sa = *(const float4*)&src[l2][0];
        float4 sb = *(const float4*)&src[l2][4];
        fma4(aL, sa, w); fma4(aH, sb, w);
      }
      float* dst = (wave == 0) ? &K0_T[lane][0] : &Q_T[wave - 1][lane][0];
      dst[0] = aL.x; dst[1] = aL.y; dst[2] = aL.z; dst[3] = aL.w;
      dst[4] = aH.x; dst[5] = aH.y; dst[6] = aH.z; dst[7] = aH.w;
    }
    __syncthreads();
    // ---------------- R: logits, p0 = sigmoid(logit), top-4 mask (wave = row)
    {
      float k0 = K0_T[lane][wave];
      float logit[6];
#pragma unroll
      for (int r = 0; r < 6; ++r) {
        float p = Q_T[r][lane][wave] * k0;
#pragma unroll
        for (int d = 1; d < 64; d <<= 1) p += __shfl_xor(p, d, 64);
        logit[r] = p * 0.125f;  // 1/sqrt(KS)
      }
      if (lane == 0) {
#pragma unroll
        for (int r = 0; r < 6; ++r) {
          int rank = 0;
#pragma unroll
          for (int r2 = 0; r2 < 6; ++r2)
            rank += (logit[r2] > logit[r]) || (logit[r2] == logit[r] && r2 < r);
          p0_l[wave][r] = sigmoidf_(logit[r]);   // softmax([l,0])[0]
          act_l[wave][r] = (rank < K_ACT) ? 1.f : 0.f;
        }
      }
    }
    __syncthreads();
    // ---------------- G1: fused gates + GRU pointwise; wave r handles rim r
    if (wave < 6) {
      const int r = wave;
      const float* Wc = Wcomb + r * 64 * 192;
      const float* Wh = Whh + r * 64 * 192;
      float4 uaL = {0,0,0,0}, uaH = {0,0,0,0}, ubL = {0,0,0,0}, ubH = {0,0,0,0},
             ucL = {0,0,0,0}, ucH = {0,0,0,0};
      float4 gaL = {0,0,0,0}, gaH = {0,0,0,0}, gbL = {0,0,0,0}, gbH = {0,0,0,0},
             gcL = {0,0,0,0}, gcH = {0,0,0,0};
#pragma unroll 4
      for (int l2 = 0; l2 < 64; ++l2) {
        const float* wr = Wc + l2 * 192 + lane;
        float w0 = wr[0], w1 = wr[64], w2 = wr[128];
        const float* vr = Wh + l2 * 192 + lane;
        float v0 = vr[0], v1 = vr[64], v2 = vr[128];
        float4 xa = *(const float4*)&xh_T[l2][0];
        float4 xb = *(const float4*)&xh_T[l2][4];
        float4 ha = *(const float4*)&h_T[r][l2][0];
        float4 hb = *(const float4*)&h_T[r][l2][4];
        fma4(uaL, xa, w0); fma4(uaH, xb, w0);
        fma4(ubL, xa, w1); fma4(ubH, xb, w1);
        fma4(ucL, xa, w2); fma4(ucH, xb, w2);
        fma4(gaL, ha, v0); fma4(gaH, hb, v0);
        fma4(gbL, ha, v1); fma4(gbH, hb, v1);
        fma4(gcL, ha, v2); fma4(gcH, hb, v2);
      }
      const float bir = bih_l[r * 192 + lane], biz = bih_l[r * 192 + 64 + lane],
                  bin = bih_l[r * 192 + 128 + lane];
      const float bhr = bhh_l[r * 192 + lane], bhz = bhh_l[r * 192 + 64 + lane],
                  bhn = bhh_l[r * 192 + 128 + lane];
      float4 holdL = *(const float4*)&h_T[r][lane][0];
      float4 holdH = *(const float4*)&h_T[r][lane][4];
      auto gru1 = [&](float p0v, float u0, float u1, float u2, float g0, float g1,
                      float g2, float hold) -> float {
        float rg = sigmoidf_(fmaf(p0v, u0, bir) + g0 + bhr);
        float zg = sigmoidf_(fmaf(p0v, u1, biz) + g1 + bhz);
        float ng = tanhf_(fmaf(p0v, u2, bin) + rg * (g2 + bhn));
        return (1.f - zg) * ng + zg * hold;
      };
      float4 hnL, hnH;
      hnL.x = gru1(p0_l[0][r], uaL.x, ubL.x, ucL.x, gaL.x, gbL.x, gcL.x, holdL.x);
      hnL.y = gru1(p0_l[1][r], uaL.y, ubL.y, ucL.y, gaL.y, gbL.y, gcL.y, holdL.y);
      hnL.z = gru1(p0_l[2][r], uaL.z, ubL.z, ucL.z, gaL.z, gbL.z, gcL.z, holdL.z);
      hnL.w = gru1(p0_l[3][r], uaL.w, ubL.w, ucL.w, gaL.w, gbL.w, gcL.w, holdL.w);
      hnH.x = gru1(p0_l[4][r], uaH.x, ubH.x, ucH.x, gaH.x, gbH.x, gcH.x, holdH.x);
      hnH.y = gru1(p0_l[5][r], uaH.y, ubH.y, ucH.y, gaH.y, gbH.y, gcH.y, holdH.y);
      hnH.z = gru1(p0_l[6][r], uaH.z, ubH.z, ucH.z, gaH.z, gbH.z, gcH.z, holdH.z);
      hnH.w = gru1(p0_l[7][r], uaH.w, ubH.w, ucH.w, gaH.w, gbH.w, gcH.w, holdH.w);
      *(float4*)&hn_T[r][lane][0] = hnL;
      *(float4*)&hn_T[r][lane][4] = hnH;
    }
    __syncthreads();
    // ---------------- C1: comm projections qc/kc (units 0..11), vc pairs (12..14)
    for (int uu = wave; uu < 15; uu += 8) {
      if (uu < 12) {
        const int r = (uu < 6) ? uu : (uu - 6);
        const float* Ws = ((uu < 6) ? Wqc : Wkc) + r * 64 * 128;
        float4 a0L = {0,0,0,0}, a0H = {0,0,0,0}, a1L = {0,0,0,0}, a1H = {0,0,0,0};
#pragma unroll 4
        for (int l2 = 0; l2 < 64; ++l2) {
          float w0 = Ws[l2 * 128 + lane], w1 = Ws[l2 * 128 + 64 + lane];
          float4 ha = *(const float4*)&hn_T[r][l2][0];
          float4 hb = *(const float4*)&hn_T[r][l2][4];
          fma4(a0L, ha, w0); fma4(a0H, hb, w0);
          fma4(a1L, ha, w1); fma4(a1H, hb, w1);
        }
        float(*dst)[9] = (uu < 6) ? qc_T[r] : kc_T[r];
        float* d0 = &dst[lane][0];
        d0[0] = a0L.x; d0[1] = a0L.y; d0[2] = a0L.z; d0[3] = a0L.w;
        d0[4] = a0H.x; d0[5] = a0H.y; d0[6] = a0H.z; d0[7] = a0H.w;
        float* d1 = &dst[lane + 64][0];
        d1[0] = a1L.x; d1[1] = a1L.y; d1[2] = a1L.z; d1[3] = a1L.w;
        d1[4] = a1H.x; d1[5] = a1H.y; d1[6] = a1H.z; d1[7] = a1H.w;
      } else {
        const int rA = (uu - 12) * 2, rB = rA + 1;
        float4 a0L = {0,0,0,0}, a0H = {0,0,0,0}, a1L = {0,0,0,0}, a1H = {0,0,0,0};
#pragma unroll 4
        for (int l2 = 0; l2 < 64; ++l2) {
          float w0 = Wvc[(rA * 64 + l2) * 64 + lane];
          float w1 = Wvc[(rB * 64 + l2) * 64 + lane];
          float4 ha = *(const float4*)&hn_T[rA][l2][0];
          float4 hb = *(const float4*)&hn_T[rA][l2][4];
          float4 hc = *(const float4*)&hn_T[rB][l2][0];
          float4 hd = *(const float4*)&hn_T[rB][l2][4];
          fma4(a0L, ha, w0); fma4(a0H, hb, w0);
          fma4(a1L, hc, w1); fma4(a1H, hd, w1);
        }
        float* d0 = &vc_T[rA][lane][0];
        d0[0] = a0L.x; d0[1] = a0L.y; d0[2] = a0L.z; d0[3] = a0L.w;
        d0[4] = a0H.x; d0[5] = a0H.y; d0[6] = a0H.z; d0[7] = a0H.w;
        float* d1 = &vc_T[rB][lane][0];
        d1[0] = a1L.x; d1[1] = a1L.y; d1[2] = a1L.z; d1[3] = a1L.w;
        d1[4] = a1H.x; d1[5] = a1H.y; d1[6] = a1H.z; d1[7] = a1H.w;
      }
    }
    __syncthreads();
    // ---------------- C2: comm attention + state update (wave = row)
    {
      const int bb = wave;
      float qcA[6], qcB[6], kcA[6], kcB[6], vcv[6];
#pragma unroll
      for (int rr = 0; rr < 6; ++rr) {
        qcA[rr] = qc_T[rr][lane][bb]; qcB[rr] = qc_T[rr][lane + 64][bb];
        kcA[rr] = kc_T[rr][lane][bb]; kcB[rr] = kc_T[rr][lane + 64][bb];
        vcv[rr] = vc_T[rr][lane][bb];
      }
      const int cOut = lane >> 4;            // output head for this lane's comm col
      const int srcLane = (cOut & 1) << 5;   // lane holding that head's reduced score
      const float inv_sq = 0.17677669529663687f;  // 1/sqrt(QC)
#pragma unroll
      for (int rr = 0; rr < 6; ++rr) {
        float sL[6], sH[6];
#pragma unroll
        for (int s = 0; s < 6; ++s) {
          float p = qcA[rr] * kcA[s];
          p += __shfl_xor(p, 1, 64); p += __shfl_xor(p, 2, 64); p += __shfl_xor(p, 4, 64);
          p += __shfl_xor(p, 8, 64); p += __shfl_xor(p, 16, 64);
          sL[s] = p * inv_sq;   // head 0 (lanes 0-31) / head 1 (lanes 32-63)
          float q = qcB[rr] * kcB[s];
          q += __shfl_xor(q, 1, 64); q += __shfl_xor(q, 2, 64); q += __shfl_xor(q, 4, 64);
          q += __shfl_xor(q, 8, 64); q += __shfl_xor(q, 16, 64);
          sH[s] = q * inv_sq;   // heads 2 / 3
        }
        float mL = sL[0], mH = sH[0];
#pragma unroll
        for (int s = 1; s < 6; ++s) { mL = fmaxf(mL, sL[s]); mH = fmaxf(mH, sH[s]); }
        float sumL = 0.f, sumH = 0.f;
#pragma unroll
        for (int s = 0; s < 6; ++s) {
          sL[s] = __expf(sL[s] - mL); sumL += sL[s];
          sH[s] = __expf(sH[s] - mH); sumH += sH[s];
        }
        float rLn = 1.f / sumL, rHn = 1.f / sumH;
        float comm = 0.f;
#pragma unroll
        for (int s = 0; s < 6; ++s) {
          float tL = __shfl(sL[s] * rLn, srcLane, 64);
          float tH = __shfl(sH[s] * rHn, srcLane, 64);
          float cp = (cOut < 2) ? tL : tH;
          comm = fmaf(cp, vcv[s], comm);
        }
        float mk = act_l[bb][rr];
        float hnv = hn_T[rr][lane][bb];
        float hov = h_T[rr][lane][bb];
        h_T[rr][lane][bb] = (mk > 0.5f) ? (hnv + comm) : hov;
      }
    }
    __syncthreads();
  }  // t

  // ---------------- final MLP head (wave = row)
  {
    const int b = b0 + wave;
    float acc[10];
#pragma unroll
    for (int o = 0; o < 10; ++o) acc[o] = 0.f;
#pragma unroll
    for (int ii = 0; ii < 6; ++ii) {
      float f = h_T[ii][lane][wave];
      const float* w = W1 + (ii * 64 + lane) * 10;
#pragma unroll
      for (int o = 0; o < 10; ++o) acc[o] = fmaf(f, w[o], acc[o]);
    }
    if (lane < 16) {
      float f = statics[(size_t)b * 16 + lane];
      const float* w = W1 + (384 + lane) * 10;
#pragma unroll
      for (int o = 0; o < 10; ++o) acc[o] = fmaf(f, w[o], acc[o]);
    }
#pragma unroll
    for (int o = 0; o < 10; ++o) {
#pragma unroll
      for (int d = 1; d < 64; d <<= 1) acc[o] += __shfl_xor(acc[o], d, 64);
    }
    if (lane == 0) {
      float o0 = b2[0], o1 = b2[1];
#pragma unroll
      for (int o = 0; o < 10; ++o) {
        float a = fmaxf(acc[o] + b1[o], 0.f);
        o0 = fmaf(a, W2[o * 2 + 0], o0);
        o1 = fmaf(a, W2[o * 2 + 1], o1);
      }
      out[(size_t)b * 2 + 0] = o0;
      out[(size_t)b * 2 + 1] = o1;
    }
  }
}

extern "C" void kernel_launch(void* const* d_in, const int* in_sizes, int n_in,
                              void* d_out, int out_size, void* d_ws, size_t ws_size,
                              hipStream_t stream) {
  const float* x       = (const float*)d_in[0];
  const float* statics = (const float*)d_in[1];
  const float* maskp   = (const float*)d_in[2];
  const float* delta   = (const float*)d_in[3];
  const float* xlast   = (const float*)d_in[4];
  const float* xmean   = (const float*)d_in[5];
  const float* wdg     = (const float*)d_in[6];
  const float* bdg     = (const float*)d_in[7];
  const float* Wk      = (const float*)d_in[8];
  const float* Wv      = (const float*)d_in[9];
  const float* Wq      = (const float*)d_in[10];
  const float* Wih     = (const float*)d_in[11];
  const float* Whh     = (const float*)d_in[12];
  const float* bih     = (const float*)d_in[13];
  const float* bhh     = (const float*)d_in[14];
  const float* Wqc     = (const float*)d_in[15];
  const float* Wkc     = (const float*)d_in[16];
  const float* Wvc     = (const float*)d_in[17];
  const float* W1      = (const float*)d_in[18];
  const float* b1      = (const float*)d_in[19];
  const float* W2      = (const float*)d_in[20];
  const float* b2      = (const float*)d_in[21];
  float* Wcomb = (float*)d_ws;  // 6*64*192 floats = 294912 B

  wcomb_kernel<<<384, 192, 0, stream>>>(Wv, Wih, Wcomb);
  rims_kernel<<<256, 512, 0, stream>>>(x, statics, maskp, delta, xlast, xmean,
                                       wdg, bdg, Wk, Wq, Whh, bih, bhh,
                                       Wqc, Wkc, Wvc, W1, b1, W2, b2,
                                       Wcomb, (float*)d_out);
}